// Round 11
// baseline (143.593 us; speedup 1.0000x reference)
//
#include <hip/hip_runtime.h>
#include <hip/hip_bf16.h>

#define F 1024
#define B_ROWS 16384

typedef short v8s __attribute__((ext_vector_type(8)));
typedef float v4f __attribute__((ext_vector_type(4)));
typedef unsigned short v8u __attribute__((ext_vector_type(8)));
typedef unsigned short ushort_t;

__device__ __forceinline__ unsigned short f2bf(float f) {
    unsigned int u = __builtin_bit_cast(unsigned int, f);
    u = (u + 0x7FFFu + ((u >> 16) & 1u)) >> 16;  // RNE
    return (unsigned short)u;
}

// Pack 2 fp32 -> 1 u32 of 2 bf16 (RNE) via the hw v_cvt_pk_bf16_f32 path.
// (__hip_bfloat162 is not trivially copyable -> extract bits via memcpy.)
__device__ __forceinline__ unsigned int cvtpk_bf16(float a, float b) {
    __hip_bfloat162 h = __float22bfloat162_rn(make_float2(a, b));
    unsigned int u;
    __builtin_memcpy(&u, &h, 4);
    return u;
}

// async global->LDS, 16B per lane. LDS dest = wave-uniform base + lane*16;
// GLOBAL source is per-lane (guide m104/m173) -- staging can gather any
// per-lane permutation from row-major x.
__device__ __forceinline__ void gload16(const void* g, void* l) {
    __builtin_amdgcn_global_load_lds(
        (const __attribute__((address_space(1))) unsigned int*)g,
        (__attribute__((address_space(3))) unsigned int*)l,
        16, 0, 0);
}

// B chunk (rb, cb) = 16-row x 32-col bf16 block stored [lane][8 bf16] in
// MFMA operand order: lane l -> row rb*16 + (l&15), cols cb*32 + (l>>4)*8+e.
// One chunk = 1 KB. B = strictly upper-triangular W ((n,k) = w_{kn}, k<n).
// N-tile nt needs K < 128*(nt+1): 56% of the full-GEMM MACs.
//
// POISON LOG (r11-r18, keep forever):
//  - fused-sigmoid epilogue in gemm: CONVICTED (MfmaUtil 20->4.4%). Separate.
//  - __launch_bounds__(256,4): VGPR+AGPR cap 128 < needed -> spill.
//  - ring-3 + no-drain barrier (r16): correct but NEUTRAL.
//  - X-pack fused as per-wave fp32 loads+cvts on MFMA path (r17): FAILED
//    38->94us. Lesson: per-WAVE global fp32 loads on the critical path.
//  - K-split jobs (r18): REGRESSION (extra prologue/epilogue, A re-reads).
//
// r19 (WIN, 128.6us): m97 structure -- both operands via global_load_lds,
// zero per-wave global loads in the loop.
// r20/r21: X-pack pass eliminated the RIGHT way: A staged as fp32 through
// global_load_lds (wave-uniform staging, latency behind the existing
// barrier; per-lane global src gathers the fragment permutation straight
// from row-major x), converted to bf16 AFTER ds_read with hardware
// v_cvt_pk_bf16_f32 (__float22bfloat162_rn; RNE, same bits as f2bf).
// Per K-step: 16 A-gloads (fp32, 2 per chunk: piece p covers cols
// quad*8+p*4..+4) + 8 B-gloads = 6 per wave; LDS 24KB/buf x 2 = 48KB.
// Prep shrinks to acc-zero + 2MB B-pack (~2us, was ~17us/96MB).

// prep: [0,64) zero rowacc; [64,576) pack triangular B.
__global__ __launch_bounds__(256) void prep_kernel(
        const float* __restrict__ w,
        ushort_t* __restrict__ Bp,
        float* __restrict__ acc) {
    const int bid  = blockIdx.x;
    const int tid  = threadIdx.x;
    const int lane = tid & 63;
    const int wave = tid >> 6;
    const int l16  = lane & 15;
    const int quad = lane >> 4;

    if (bid < 64) {
        acc[bid * 256 + tid] = 0.0f;
    } else {
        const int c  = (bid - 64) * 4 + wave;    // 0..2047
        const int n  = (c >> 5) * 16 + l16;      // output-col axis
        const int k0 = (c & 31) * 32 + quad * 8; // contraction axis
        v8u o;
#pragma unroll
        for (int e = 0; e < 8; ++e) {
            const int k = k0 + e;
            float v = 0.0f;
            if (k < n) {  // strictly upper: pair (k,n), k<n
                const int idx = k * (F - 1) - (k * (k - 1)) / 2 + (n - k - 1);
                v = w[idx];  // scattered read; w = 2MB, L2-resident
            }
            o[e] = f2bf(v);
        }
        *(v8u*)(Bp + (size_t)c * 512 + lane * 8) = o;
    }
}

// m97-structure GEMM, triangular-K, fp32-A direct staging (r20/r21).
// 128x128 block, 2x2 waves, K-step 32.
// LDS per buffer: A = 8 chunks x 2KB fp32 (piece0|piece1, each 64x16B),
// B = 8 chunks x 1KB bf16. 24KB x 2 bufs = 48KB.
__global__ __launch_bounds__(256, 3) void gemm_kernel(
        const ushort_t* __restrict__ Bp,   // packed triangular-W chunks
        const float*   __restrict__ Xf,    // fp32 X (A operand + epilogue)
        float*         __restrict__ rowacc) {
    __shared__ char Ls[2 * 24 * 1024];

    const int f   = blockIdx.x;          // 0..1023
    const int xcd = f & 7;
    const int g   = f >> 3;              // 0..127
    const int y   = g & 15;
    const int nt  = 7 - (g >> 4);        // heavy (nt=7) first
    const int blockM = (xcd * 16 + y) * 128;
    const int blockN = nt * 128;
    const int tEnd   = 4 * (nt + 1);     // K-steps of 32: K < 128*(nt+1)

    const int tid   = threadIdx.x;
    const int lane  = tid & 63;
    const int wave  = tid >> 6;
    const int waveM = wave >> 1;
    const int waveN = wave & 1;
    const int quad  = lane >> 4;
    const int l16   = lane & 15;

    const int ngB = nt * 8;              // first B row-group (of 8)

    // Staging: 24 gloads/step, 6 per wave. qq<16: A chunk ac=qq>>1, piece
    // p=qq&1 (fp32, per-lane gather from row-major x: lane -> row l16 of
    // chunk, 4 floats at cols t*32 + quad*8 + p*4). qq>=16: B chunk bc.
#define STAGE(t, buf)                                                          \
    {                                                                          \
        _Pragma("unroll")                                                      \
        for (int q = 0; q < 6; ++q) {                                          \
            const int qq = wave * 6 + q;                                       \
            if (qq < 16) {                                                     \
                const int ac = qq >> 1, p = qq & 1;                            \
                gload16(Xf + (size_t)(blockM + ac * 16 + l16) * F              \
                            + (t) * 32 + quad * 8 + p * 4,                     \
                        Ls + (buf) * 24576 + ac * 2048 + p * 1024);            \
            } else {                                                           \
                const int bc = qq - 16;                                        \
                gload16(Bp + ((size_t)(ngB + bc) * 32 + (t)) * 512 + lane * 8, \
                        Ls + (buf) * 24576 + 16384 + bc * 1024);               \
            }                                                                  \
        }                                                                      \
    }

    v4f acc[4][4];
#pragma unroll
    for (int i = 0; i < 4; i++)
#pragma unroll
        for (int j = 0; j < 4; j++) acc[i][j] = (v4f)(0.0f);

    v8s afr[4], bfr[4];

    // prologue: stage K-step 0 (full drain via __syncthreads, prologue only)
    STAGE(0, 0)
    __syncthreads();

    for (int t = 0; t < tEnd; ++t) {
        const int  buf  = t & 1;
        const bool more = (t + 1 < tEnd);
        if (more) STAGE(t + 1, buf ^ 1)  // in flight across this step

        // A: 2x ds_read_b128 (fp32 pieces) + hw cvt_pk to bf16 frag
#pragma unroll
        for (int mi = 0; mi < 4; ++mi) {
            const char* Ab = Ls + buf * 24576 + (waveM * 4 + mi) * 2048 + lane * 16;
            v4f lo = *(const v4f*)(Ab);
            v4f hi = *(const v4f*)(Ab + 1024);
            uint4 pk;
            pk.x = cvtpk_bf16(lo[0], lo[1]);
            pk.y = cvtpk_bf16(lo[2], lo[3]);
            pk.z = cvtpk_bf16(hi[0], hi[1]);
            pk.w = cvtpk_bf16(hi[2], hi[3]);
            afr[mi] = __builtin_bit_cast(v8s, pk);
        }
#pragma unroll
        for (int ni = 0; ni < 4; ++ni)
            bfr[ni] = *(const v8s*)(Ls + buf * 24576 + 16384
                                    + (waveN * 4 + ni) * 1024 + lane * 16);

#pragma unroll
        for (int mi = 0; mi < 4; ++mi)
#pragma unroll
            for (int ni = 0; ni < 4; ++ni)
                acc[mi][ni] = __builtin_amdgcn_mfma_f32_16x16x32_bf16(
                    afr[mi], bfr[ni], acc[mi][ni], 0, 0, 0);

        if (more) __syncthreads();  // gates buffer reuse; staging t+1 landed
    }
#undef STAGE

    // Epilogue: C/D mapping (verified): col = lane&15, row = quad*4 + reg.
#pragma unroll
    for (int mi = 0; mi < 4; mi++) {
#pragma unroll
        for (int r = 0; r < 4; r++) {
            const int b = blockM + waveM * 64 + mi * 16 + quad * 4 + r;
            const float* xr = Xf + (size_t)b * F + blockN + waveN * 64 + l16;
            float pv = acc[mi][0][r] * xr[0]
                     + acc[mi][1][r] * xr[16]
                     + acc[mi][2][r] * xr[32]
                     + acc[mi][3][r] * xr[48];
            pv += __shfl_xor(pv, 1);
            pv += __shfl_xor(pv, 2);
            pv += __shfl_xor(pv, 4);
            pv += __shfl_xor(pv, 8);
            if (l16 == 0) atomicAdd(&rowacc[b], pv);
        }
    }
}

__global__ void sigmoid_kernel(const float* __restrict__ acc, float* __restrict__ out) {
    int b = blockIdx.x * blockDim.x + threadIdx.x;
    out[b] = 1.0f / (1.0f + __expf(-acc[b]));
}

// Correctness fallback if workspace is too small: direct per-row computation.
__global__ void fallback_kernel(const float* __restrict__ x, const float* __restrict__ w,
                                float* __restrict__ out) {
    __shared__ float xs[F];
    __shared__ float partial[4];
    const int b = blockIdx.x;
    for (int i = threadIdx.x; i < F; i += 256) xs[i] = x[(size_t)b * F + i];
    __syncthreads();
    float s = 0.0f;
    for (int i = threadIdx.x; i < F - 1; i += 256) {
        const float xi = xs[i];
        const int kbase = i * (F - 1) - (i * (i - 1)) / 2 - i - 1;
        for (int j = i + 1; j < F; j++) s += w[kbase + j] * xi * xs[j];
    }
    for (int off = 32; off; off >>= 1) s += __shfl_down(s, off);
    if ((threadIdx.x & 63) == 0) partial[threadIdx.x >> 6] = s;
    __syncthreads();
    if (threadIdx.x == 0) {
        float t = partial[0] + partial[1] + partial[2] + partial[3];
        out[b] = 1.0f / (1.0f + __expf(-t));
    }
}

extern "C" void kernel_launch(void* const* d_in, const int* in_sizes, int n_in,
                              void* d_out, int out_size, void* d_ws, size_t ws_size,
                              hipStream_t stream) {
    const float* x = (const float*)d_in[0];
    const float* w = (const float*)d_in[1];
    float* out = (float*)d_out;

    const size_t acc_bytes = 65536;                       // 16384 fp32 (rounded)
    const size_t B_bytes   = (size_t)F * F * 2;           // 2 MiB packed triangular W
    const size_t needed = acc_bytes + B_bytes;

    if (ws_size < needed) {
        fallback_kernel<<<B_ROWS, 256, 0, stream>>>(x, w, out);
        return;
    }

    float*    acc = (float*)d_ws;
    ushort_t* Bp  = (ushort_t*)((char*)d_ws + acc_bytes);

    // prep: 64 (acc zero) + 512 (pack B)  -- no X-pack pass
    prep_kernel<<<64 + 512, 256, 0, stream>>>(w, Bp, acc);
    // 128 M-tiles x 8 N-tiles; per-block K-extent 4*(nt+1) K-steps of 32
    gemm_kernel<<<1024, 256, 0, stream>>>(Bp, x, acc);
    sigmoid_kernel<<<B_ROWS / 256, 256, 0, stream>>>(acc, out);
}

// Round 12
// 128.175 us; speedup vs baseline: 1.1203x; 1.1203x over previous
//
#include <hip/hip_runtime.h>
#include <hip/hip_bf16.h>

#define F 1024
#define B_ROWS 16384

typedef short v8s __attribute__((ext_vector_type(8)));
typedef float v4f __attribute__((ext_vector_type(4)));
typedef unsigned short v8u __attribute__((ext_vector_type(8)));
typedef unsigned short ushort_t;

__device__ __forceinline__ unsigned short f2bf(float f) {
    unsigned int u = __builtin_bit_cast(unsigned int, f);
    u = (u + 0x7FFFu + ((u >> 16) & 1u)) >> 16;  // RNE
    return (unsigned short)u;
}

// async global->LDS, 16B per lane. LDS dest = wave-uniform base + lane*16.
__device__ __forceinline__ void gload_lds16(const ushort_t* g, ushort_t* l) {
    __builtin_amdgcn_global_load_lds(
        (const __attribute__((address_space(1))) unsigned int*)g,
        (__attribute__((address_space(3))) unsigned int*)l,
        16, 0, 0);
}

// Chunk (rb, cb) = 16-row x 32-col bf16 block stored [lane][8 bf16] in MFMA
// operand order: lane l -> row rb*16 + (l&15), cols cb*32 + (l>>4)*8..+8.
// One chunk = 1 KB. B = strictly upper-triangular W ((n,k) = w_{kn}, k<n).
// N-tile nt needs K < 128*(nt+1): 56% of the full-GEMM MACs.
//
// POISON LOG (keep forever):
//  - fused-sigmoid epilogue in gemm: CONVICTED (MfmaUtil 20->4.4%). Separate.
//  - __launch_bounds__(256,4) ON THE OLD PING-PONG LOOP (r12): spill at
//    136 regs needed vs 128 cap. The m97 loop needs ~96-110 -> retrying
//    (256,4) HERE is this round's single lever; spill signature =
//    VGPR_Count<64 + gemm>=100us -> revert flag only.
//  - ring-3 + no-drain barrier (r16): correct but NEUTRAL.
//  - X-pack fused as per-wave fp32 loads+cvts on MFMA path (r17): FAILED.
//  - K-split jobs (r18): REGRESSION (extra prologue/epilogue, A re-reads).
//  - fp32-A staged via global_load_lds + post-LDS cvt_pk (r20/r21): FAILED
//    gemm 34->65us. cvt+extra ds_reads on critical path (VALUBusy 23%) AND
//    the A-gather source strides 4KB/lane (16 cache lines per gload) vs
//    Xp's contiguous 1KB. The X-pack pre-pass amortizes conversion AND
//    linearizes the staging source -- it stays.
//
// r19 (WIN, 128.6us): m97 structure -- both operands via global_load_lds
// from packed chunks, zero per-wave global loads in the loop.

// prep: [0,64) zero rowacc; [64,576) pack triangular B; [576,8768) pack X.
__global__ __launch_bounds__(256) void prep_kernel(
        const float* __restrict__ w, const float* __restrict__ x,
        ushort_t* __restrict__ Bp, ushort_t* __restrict__ Xp,
        float* __restrict__ acc) {
    const int bid  = blockIdx.x;
    const int tid  = threadIdx.x;
    const int lane = tid & 63;
    const int wave = tid >> 6;
    const int l16  = lane & 15;
    const int quad = lane >> 4;

    if (bid < 64) {
        acc[bid * 256 + tid] = 0.0f;
    } else if (bid < 576) {
        const int c  = (bid - 64) * 4 + wave;    // 0..2047
        const int n  = (c >> 5) * 16 + l16;      // output-col axis
        const int k0 = (c & 31) * 32 + quad * 8; // contraction axis
        v8u o;
#pragma unroll
        for (int e = 0; e < 8; ++e) {
            const int k = k0 + e;
            float v = 0.0f;
            if (k < n) {  // strictly upper: pair (k,n), k<n
                const int idx = k * (F - 1) - (k * (k - 1)) / 2 + (n - k - 1);
                v = w[idx];  // scattered read; w = 2MB, L2-resident
            }
            o[e] = f2bf(v);
        }
        *(v8u*)(Bp + (size_t)c * 512 + lane * 8) = o;
    } else {
        const int c  = (bid - 576) * 4 + wave;  // 0..32767
        const int r  = (c >> 5) * 16 + l16;     // X row
        const int k0 = (c & 31) * 32 + quad * 8;
        const float* src = x + (size_t)r * F + k0;
        float4 v0 = *(const float4*)(src);
        float4 v1 = *(const float4*)(src + 4);
        v8u o;
        o[0] = f2bf(v0.x); o[1] = f2bf(v0.y); o[2] = f2bf(v0.z); o[3] = f2bf(v0.w);
        o[4] = f2bf(v1.x); o[5] = f2bf(v1.y); o[6] = f2bf(v1.z); o[7] = f2bf(v1.w);
        *(v8u*)(Xp + (size_t)c * 512 + lane * 8) = o;
    }
}

// m97-structure GEMM, triangular-K. 128x128 block, 2x2 waves, K-step 32.
// LDS: 2 bufs x (8 A-chunks + 8 B-chunks) x 1KB = 32 KB.
// r22: (256,4) -- the single lever vs the 128.6us r19 build. The m97 loop
// holds only afr[4]+bfr[4] fragments; 64 AGPR + ~64 ArchVGPR should fit
// the 128/wave budget -> 4 blocks/CU (+33% TLP for the latency stalls).
__global__ __launch_bounds__(256, 4) void gemm_kernel(
        const ushort_t* __restrict__ Xp,   // packed X chunks
        const ushort_t* __restrict__ Bp,   // packed triangular-W chunks
        const float*   __restrict__ Xf,    // fp32 X (epilogue)
        float*         __restrict__ rowacc) {
    __shared__ ushort_t Ls[2 * 16 * 512];  // [buf][slot 0-7=A, 8-15=B][1KB]

    const int f   = blockIdx.x;          // 0..1023
    const int xcd = f & 7;
    const int g   = f >> 3;              // 0..127
    const int y   = g & 15;
    const int nt  = 7 - (g >> 4);        // heavy (nt=7) first
    const int blockM = (xcd * 16 + y) * 128;
    const int blockN = nt * 128;
    const int tEnd   = 4 * (nt + 1);     // K-steps of 32: K < 128*(nt+1)

    const int tid   = threadIdx.x;
    const int lane  = tid & 63;
    const int wave  = tid >> 6;
    const int waveM = wave >> 1;
    const int waveN = wave & 1;
    const int quad  = lane >> 4;
    const int l16   = lane & 15;

    const int mgBase = blockM >> 4;      // first A row-group (of 8)
    const int ngB    = nt * 8;           // first B row-group (of 8)

    // Staging: waves 0-1 stage the 8 A-chunks, waves 2-3 the 8 B-chunks.
    // Per wave 4 gload_lds16 per K-step; wave-uniform LDS dest + lane*16.
    const bool stageA = (wave < 2);
    const int  qBase  = (wave & 1) * 4;  // chunk offset within A or B half
    const ushort_t* gsrc0 = stageA
        ? Xp + ((size_t)(mgBase + qBase) * 32) * 512
        : Bp + ((size_t)(ngB  + qBase) * 32) * 512;
    const int slot0 = (stageA ? 0 : 8) + qBase;

#define STAGE(t, buf)                                                          \
    {                                                                          \
        _Pragma("unroll")                                                      \
        for (int q = 0; q < 4; ++q) {                                          \
            gload_lds16(gsrc0 + ((size_t)q * 32 + (t)) * 512 + lane * 8,       \
                        Ls + ((buf) * 16 + slot0 + q) * 512);                  \
        }                                                                      \
    }

    v4f acc[4][4];
#pragma unroll
    for (int i = 0; i < 4; i++)
#pragma unroll
        for (int j = 0; j < 4; j++) acc[i][j] = (v4f)(0.0f);

    v8s afr[4], bfr[4];

    // prologue: stage K-step 0
    STAGE(0, 0)
    __syncthreads();

    for (int t = 0; t < tEnd; ++t) {
        const int  buf  = t & 1;
        const bool more = (t + 1 < tEnd);
        if (more) STAGE(t + 1, buf ^ 1)  // in flight across this step

#pragma unroll
        for (int mi = 0; mi < 4; ++mi)
            afr[mi] = *(const v8s*)(Ls + (buf * 16 + waveM * 4 + mi) * 512 + lane * 8);
#pragma unroll
        for (int ni = 0; ni < 4; ++ni)
            bfr[ni] = *(const v8s*)(Ls + (buf * 16 + 8 + waveN * 4 + ni) * 512 + lane * 8);

#pragma unroll
        for (int mi = 0; mi < 4; ++mi)
#pragma unroll
            for (int ni = 0; ni < 4; ++ni)
                acc[mi][ni] = __builtin_amdgcn_mfma_f32_16x16x32_bf16(
                    afr[mi], bfr[ni], acc[mi][ni], 0, 0, 0);

        if (more) __syncthreads();  // gates buffer reuse; staging t+1 landed
    }
#undef STAGE

    // Epilogue: C/D mapping (verified): col = lane&15, row = quad*4 + reg.
#pragma unroll
    for (int mi = 0; mi < 4; mi++) {
#pragma unroll
        for (int r = 0; r < 4; r++) {
            const int b = blockM + waveM * 64 + mi * 16 + quad * 4 + r;
            const float* xr = Xf + (size_t)b * F + blockN + waveN * 64 + l16;
            float pv = acc[mi][0][r] * xr[0]
                     + acc[mi][1][r] * xr[16]
                     + acc[mi][2][r] * xr[32]
                     + acc[mi][3][r] * xr[48];
            pv += __shfl_xor(pv, 1);
            pv += __shfl_xor(pv, 2);
            pv += __shfl_xor(pv, 4);
            pv += __shfl_xor(pv, 8);
            if (l16 == 0) atomicAdd(&rowacc[b], pv);
        }
    }
}

__global__ void sigmoid_kernel(const float* __restrict__ acc, float* __restrict__ out) {
    int b = blockIdx.x * blockDim.x + threadIdx.x;
    out[b] = 1.0f / (1.0f + __expf(-acc[b]));
}

// Correctness fallback if workspace is too small: direct per-row computation.
__global__ void fallback_kernel(const float* __restrict__ x, const float* __restrict__ w,
                                float* __restrict__ out) {
    __shared__ float xs[F];
    __shared__ float partial[4];
    const int b = blockIdx.x;
    for (int i = threadIdx.x; i < F; i += 256) xs[i] = x[(size_t)b * F + i];
    __syncthreads();
    float s = 0.0f;
    for (int i = threadIdx.x; i < F - 1; i += 256) {
        const float xi = xs[i];
        const int kbase = i * (F - 1) - (i * (i - 1)) / 2 - i - 1;
        for (int j = i + 1; j < F; j++) s += w[kbase + j] * xi * xs[j];
    }
    for (int off = 32; off; off >>= 1) s += __shfl_down(s, off);
    if ((threadIdx.x & 63) == 0) partial[threadIdx.x >> 6] = s;
    __syncthreads();
    if (threadIdx.x == 0) {
        float t = partial[0] + partial[1] + partial[2] + partial[3];
        out[b] = 1.0f / (1.0f + __expf(-t));
    }
}

extern "C" void kernel_launch(void* const* d_in, const int* in_sizes, int n_in,
                              void* d_out, int out_size, void* d_ws, size_t ws_size,
                              hipStream_t stream) {
    const float* x = (const float*)d_in[0];
    const float* w = (const float*)d_in[1];
    float* out = (float*)d_out;

    const size_t acc_bytes = 65536;                       // 16384 fp32 (rounded)
    const size_t B_bytes   = (size_t)F * F * 2;           // 2 MiB packed triangular W
    const size_t Xp_bytes  = (size_t)B_ROWS * F * 2;      // 32 MiB packed X
    const size_t needed = acc_bytes + B_bytes + Xp_bytes;

    if (ws_size < needed) {
        fallback_kernel<<<B_ROWS, 256, 0, stream>>>(x, w, out);
        return;
    }

    float*    acc = (float*)d_ws;
    ushort_t* Bp  = (ushort_t*)((char*)d_ws + acc_bytes);
    ushort_t* Xp  = (ushort_t*)((char*)d_ws + acc_bytes + B_bytes);

    // prep: 64 (acc zero) + 512 (pack B) + 8192 (pack X)
    prep_kernel<<<64 + 512 + 8192, 256, 0, stream>>>(w, x, Bp, Xp, acc);
    // 128 M-tiles x 8 N-tiles; per-block K-extent 4*(nt+1) K-steps of 32
    gemm_kernel<<<1024, 256, 0, stream>>>(Xp, Bp, x, acc);
    sigmoid_kernel<<<B_ROWS / 256, 256, 0, stream>>>(acc, out);
}